// Round 1
// baseline (858.650 us; speedup 1.0000x reference)
//
#include <hip/hip_runtime.h>
#include <hip/hip_bf16.h>

typedef __attribute__((ext_vector_type(8))) __bf16 bf16x8;
typedef __attribute__((ext_vector_type(4))) float f32x4;

#define MDIM 16384  // B*T
#define HDIM 2048
#define IDIM 512
#define ODIM 512

static __device__ __forceinline__ unsigned short f2bf(float f) {
  // round-to-nearest-even f32 -> bf16 (values here are finite, no NaN path needed)
  unsigned int u = __float_as_uint(f);
  unsigned int r = (u + 0x7fffu + ((u >> 16) & 1u)) >> 16;
  return (unsigned short)r;
}

// ---------------- W_dec f32 -> bf16 ----------------
__global__ void cvt_bf16_kernel(const float* __restrict__ src,
                                unsigned short* __restrict__ dst, int n) {
  int i = (blockIdx.x * 256 + threadIdx.x) * 4;
  if (i >= n) return;
  float4 v = *(const float4*)(src + i);
  unsigned int a = (unsigned int)f2bf(v.x) | ((unsigned int)f2bf(v.y) << 16);
  unsigned int b = (unsigned int)f2bf(v.z) | ((unsigned int)f2bf(v.w) << 16);
  uint2 st; st.x = a; st.y = b;
  *(uint2*)(dst + i) = st;
}

// ---------------- GEMM1: h = x @ W_enc^T + b_enc, zero where mask_prev ----------------
// f32 SIMT, 128x128 tile, BK=16, 256 threads, 8x8 micro-tile (split 4+4 at stride 64)
__global__ __launch_bounds__(256) void gemm1_kernel(
    const float* __restrict__ x,     // [M, IDIM]
    const float* __restrict__ wenc,  // [HDIM, IDIM] (K-major, B^T layout)
    const float* __restrict__ benc,  // [HDIM]
    const int* __restrict__ maskp,   // [M, HDIM]
    float* __restrict__ h) {         // [M, HDIM]
  __shared__ __align__(16) float As[16][132];  // [k][m], +4 pad breaks bank aliasing
  __shared__ __align__(16) float Bs[16][132];  // [k][n]
  const int t = threadIdx.x;
  const int tx = t & 15, ty = t >> 4;
  const int m0 = blockIdx.y * 128;
  const int n0 = blockIdx.x * 128;
  const int r0 = t >> 2;          // 0..63 staging row
  const int k4 = (t & 3) * 4;     // k sub-offset

  const float* pa0 = x + (size_t)(m0 + r0) * IDIM + k4;
  const float* pa1 = x + (size_t)(m0 + 64 + r0) * IDIM + k4;
  const float* pb0 = wenc + (size_t)(n0 + r0) * IDIM + k4;
  const float* pb1 = wenc + (size_t)(n0 + 64 + r0) * IDIM + k4;

  float acc[8][8];
#pragma unroll
  for (int i = 0; i < 8; ++i)
#pragma unroll
    for (int j = 0; j < 8; ++j) acc[i][j] = 0.f;

  for (int kt = 0; kt < IDIM; kt += 16) {
    float4 a0 = *(const float4*)(pa0 + kt);
    float4 a1 = *(const float4*)(pa1 + kt);
    float4 b0 = *(const float4*)(pb0 + kt);
    float4 b1 = *(const float4*)(pb1 + kt);
    __syncthreads();
#pragma unroll
    for (int j = 0; j < 4; ++j) {
      As[k4 + j][r0]      = ((const float*)&a0)[j];
      As[k4 + j][64 + r0] = ((const float*)&a1)[j];
      Bs[k4 + j][r0]      = ((const float*)&b0)[j];
      Bs[k4 + j][64 + r0] = ((const float*)&b1)[j];
    }
    __syncthreads();
#pragma unroll
    for (int k = 0; k < 16; ++k) {
      float4 av0 = *(const float4*)&As[k][ty * 4];
      float4 av1 = *(const float4*)&As[k][64 + ty * 4];
      float4 bv0 = *(const float4*)&Bs[k][tx * 4];
      float4 bv1 = *(const float4*)&Bs[k][64 + tx * 4];
      float am[8] = {av0.x, av0.y, av0.z, av0.w, av1.x, av1.y, av1.z, av1.w};
      float bm[8] = {bv0.x, bv0.y, bv0.z, bv0.w, bv1.x, bv1.y, bv1.z, bv1.w};
#pragma unroll
      for (int i = 0; i < 8; ++i)
#pragma unroll
        for (int j = 0; j < 8; ++j) acc[i][j] += am[i] * bm[j];
    }
  }
  // epilogue: + bias, zero where mask_prev > 0
  float4 be0 = *(const float4*)(benc + n0 + tx * 4);
  float4 be1 = *(const float4*)(benc + n0 + 64 + tx * 4);
  float bb[8] = {be0.x, be0.y, be0.z, be0.w, be1.x, be1.y, be1.z, be1.w};
#pragma unroll
  for (int i = 0; i < 8; ++i) {
    int m = m0 + ((i < 4) ? (ty * 4 + i) : (64 + ty * 4 + (i - 4)));
    const int* mrow = maskp + (size_t)m * HDIM + n0;
    int4 mk0 = *(const int4*)(mrow + tx * 4);
    int4 mk1 = *(const int4*)(mrow + 64 + tx * 4);
    int mm[8] = {mk0.x, mk0.y, mk0.z, mk0.w, mk1.x, mk1.y, mk1.z, mk1.w};
    float o[8];
#pragma unroll
    for (int j = 0; j < 8; ++j) {
      float v = acc[i][j] + bb[j];
      o[j] = (mm[j] > 0) ? 0.f : v;
    }
    float* hrow = h + (size_t)m * HDIM + n0;
    float4 s0 = {o[0], o[1], o[2], o[3]};
    float4 s1 = {o[4], o[5], o[6], o[7]};
    *(float4*)(hrow + tx * 4) = s0;
    *(float4*)(hrow + 64 + tx * 4) = s1;
  }
}

// ---------------- selection: exact top-512 / top-256 of h^2 per row ----------------
// One block (256 thr) per row. Keys = f32 bits of h*h (non-negative -> uint order).
// MSB-first bit-fixing bisection finds the exact kth-largest VALUE; ties filled in
// ascending-index order to match jax.lax.top_k semantics.
// Writes mask_prev_new over the h buffer (registers hold h first; only own lanes' addrs).
__global__ __launch_bounds__(256) void select_kernel(
    float* __restrict__ hbuf,           // in: h [M,HDIM]; out: mask_prev_new
    const int* __restrict__ maskp,      // [M, HDIM]
    unsigned short* __restrict__ hs) {  // out: h*mask_share as bf16 [M,HDIM]
  const int row = blockIdx.x;
  const int t = threadIdx.x;
  const int lane = t & 63;
  const int w = t >> 6;
  __shared__ int red[4];

  float* hrow = hbuf + (size_t)row * HDIM;
  float hv[8];
  *(float4*)&hv[0] = *(const float4*)(hrow + t * 8);
  *(float4*)&hv[4] = *(const float4*)(hrow + t * 8 + 4);
  unsigned int key[8];
#pragma unroll
  for (int i = 0; i < 8; ++i) key[i] = __float_as_uint(hv[i] * hv[i]);

  unsigned int v512 = 0, v256 = 0;  // will become the 512th / 256th largest key
  for (int b = 31; b >= 0; --b) {
    unsigned int c1 = v512 | (1u << b);
    unsigned int c2 = v256 | (1u << b);
    int cnt = 0;  // packed: low16 = count(key>=c1), high16 = count(key>=c2)
#pragma unroll
    for (int i = 0; i < 8; ++i) {
      cnt += (key[i] >= c1) ? 1 : 0;
      cnt += (key[i] >= c2) ? (1 << 16) : 0;
    }
#pragma unroll
    for (int d = 1; d < 64; d <<= 1) cnt += __shfl_xor(cnt, d, 64);
    if (lane == 0) red[w] = cnt;
    __syncthreads();
    int tot = red[0] + red[1] + red[2] + red[3];
    __syncthreads();
    if ((tot & 0xffff) >= 512) v512 = c1;
    if ((tot >> 16) >= 256) v256 = c2;
  }
  // strictly-greater counts -> number of tie slots to fill
  int g = 0;
#pragma unroll
  for (int i = 0; i < 8; ++i) {
    g += (key[i] > v512) ? 1 : 0;
    g += (key[i] > v256) ? (1 << 16) : 0;
  }
#pragma unroll
  for (int d = 1; d < 64; d <<= 1) g += __shfl_xor(g, d, 64);
  if (lane == 0) red[w] = g;
  __syncthreads();
  g = red[0] + red[1] + red[2] + red[3];
  __syncthreads();
  const int r512 = 512 - (g & 0xffff);
  const int r256 = 256 - (g >> 16);

  // exclusive scan (thread order == index order) of per-thread tie counts
  int tc = 0;
#pragma unroll
  for (int i = 0; i < 8; ++i) {
    tc += (key[i] == v512) ? 1 : 0;
    tc += (key[i] == v256) ? (1 << 16) : 0;
  }
  int sc = tc;
#pragma unroll
  for (int d = 1; d < 64; d <<= 1) {
    int o = __shfl_up(sc, d, 64);
    if (lane >= d) sc += o;
  }
  if (lane == 63) red[w] = sc;
  __syncthreads();
  int excl = sc - tc;
  for (int i = 0; i < w; ++i) excl += red[i];
  int run512 = excl & 0xffff;
  int run256 = (excl >> 16) & 0xffff;

  const int* mrow = maskp + (size_t)row * HDIM;
  int4 mp0 = *(const int4*)(mrow + t * 8);
  int4 mp1 = *(const int4*)(mrow + t * 8 + 4);
  int mm[8] = {mp0.x, mp0.y, mp0.z, mp0.w, mp1.x, mp1.y, mp1.z, mp1.w};

  float mpn[8];
  unsigned int hb[4];
#pragma unroll
  for (int i = 0; i < 8; ++i) {
    bool share, cur;
    if (key[i] > v512) share = true;
    else if (key[i] == v512) { share = (run512 < r512); run512++; }
    else share = false;
    if (key[i] > v256) cur = true;
    else if (key[i] == v256) { cur = (run256 < r256); run256++; }
    else cur = false;
    mpn[i] = (float)mm[i] + (cur ? 1.0f : 0.0f);
    unsigned short bbits = f2bf(share ? hv[i] : 0.0f);
    if (i & 1) hb[i >> 1] |= ((unsigned int)bbits << 16);
    else hb[i >> 1] = (unsigned int)bbits;
  }
  float4 s0 = {mpn[0], mpn[1], mpn[2], mpn[3]};
  float4 s1 = {mpn[4], mpn[5], mpn[6], mpn[7]};
  *(float4*)(hrow + t * 8) = s0;
  *(float4*)(hrow + t * 8 + 4) = s1;
  uint4 hstore = {hb[0], hb[1], hb[2], hb[3]};
  *(uint4*)(hs + (size_t)row * HDIM + t * 8) = hstore;
}

// ---------------- GEMM2: out = hs @ W_dec^T + b_dec (bf16 MFMA, m97 pattern) ----------------
// 128x128 tile, BK=32, 4 waves in 2x2, each wave 64x64 via 4x4 MFMA 16x16x32 subtiles.
__global__ __launch_bounds__(256) void gemm2_kernel(
    const unsigned short* __restrict__ A,  // hs bf16 [M, HDIM]
    const unsigned short* __restrict__ B,  // W_dec bf16 [ODIM, HDIM] (B^T layout)
    const float* __restrict__ bdec,        // [ODIM]
    float* __restrict__ out) {             // [M, ODIM] f32
  __shared__ __align__(16) __bf16 As[128 * 32];
  __shared__ __align__(16) __bf16 Bs[128 * 32];
  const int t = threadIdx.x;
  const int lane = t & 63;
  const int w = t >> 6;
  const int wm = w >> 1, wn = w & 1;
  const int m0 = blockIdx.y * 128;
  const int n0 = blockIdx.x * 128;
  const int r = t >> 2;          // staging row 0..63
  const int k8 = (t & 3) * 8;    // 8-bf16 chunk offset within BK=32

  f32x4 acc[4][4];
#pragma unroll
  for (int i = 0; i < 4; ++i)
#pragma unroll
    for (int j = 0; j < 4; ++j) acc[i][j] = (f32x4){0.f, 0.f, 0.f, 0.f};

  const int la = lane & 15;
  const int kq = (lane >> 4) * 8;

  for (int kt = 0; kt < HDIM; kt += 32) {
    uint4 a0 = *(const uint4*)(A + (size_t)(m0 + r) * HDIM + kt + k8);
    uint4 a1 = *(const uint4*)(A + (size_t)(m0 + 64 + r) * HDIM + kt + k8);
    uint4 b0 = *(const uint4*)(B + (size_t)(n0 + r) * HDIM + kt + k8);
    uint4 b1 = *(const uint4*)(B + (size_t)(n0 + 64 + r) * HDIM + kt + k8);
    __syncthreads();
    *(uint4*)&As[r * 32 + k8] = a0;
    *(uint4*)&As[(64 + r) * 32 + k8] = a1;
    *(uint4*)&Bs[r * 32 + k8] = b0;
    *(uint4*)&Bs[(64 + r) * 32 + k8] = b1;
    __syncthreads();
    bf16x8 af[4], bg[4];
#pragma unroll
    for (int mi = 0; mi < 4; ++mi)
      af[mi] = *(const bf16x8*)&As[(wm * 64 + mi * 16 + la) * 32 + kq];
#pragma unroll
    for (int ni = 0; ni < 4; ++ni)
      bg[ni] = *(const bf16x8*)&Bs[(wn * 64 + ni * 16 + la) * 32 + kq];
#pragma unroll
    for (int mi = 0; mi < 4; ++mi)
#pragma unroll
      for (int ni = 0; ni < 4; ++ni)
        acc[mi][ni] = __builtin_amdgcn_mfma_f32_16x16x32_bf16(
            af[mi], bg[ni], acc[mi][ni], 0, 0, 0);
  }
  // C/D layout: col = lane&15 (n), row = (lane>>4)*4 + reg (m)
  const int rq = (lane >> 4) * 4;
#pragma unroll
  for (int mi = 0; mi < 4; ++mi) {
#pragma unroll
    for (int ni = 0; ni < 4; ++ni) {
      int n = n0 + wn * 64 + ni * 16 + la;
      float bd = bdec[n];
#pragma unroll
      for (int rr = 0; rr < 4; ++rr) {
        int m = m0 + wm * 64 + mi * 16 + rq + rr;
        out[(size_t)m * ODIM + n] = acc[mi][ni][rr] + bd;
      }
    }
  }
}

extern "C" void kernel_launch(void* const* d_in, const int* in_sizes, int n_in,
                              void* d_out, int out_size, void* d_ws, size_t ws_size,
                              hipStream_t stream) {
  const float* x = (const float*)d_in[0];          // [8,2048,512]
  const int* mask_prev = (const int*)d_in[1];      // [8,2048,2048]
  const float* W_enc = (const float*)d_in[2];      // [2048,512]
  const float* b_enc = (const float*)d_in[3];      // [2048]
  const float* W_dec = (const float*)d_in[4];      // [512,2048]
  const float* b_dec = (const float*)d_in[5];      // [512]

  float* out = (float*)d_out;                         // [M, ODIM]
  float* hbuf = out + (size_t)MDIM * ODIM;            // h staged in mask_prev_new slot
  unsigned short* hs = (unsigned short*)d_ws;         // [M, HDIM] bf16 (64 MB)
  unsigned short* wdec = hs + (size_t)MDIM * HDIM;    // [ODIM, HDIM] bf16 (2 MB)

  cvt_bf16_kernel<<<dim3((ODIM * HDIM) / (256 * 4)), dim3(256), 0, stream>>>(
      W_dec, wdec, ODIM * HDIM);
  gemm1_kernel<<<dim3(HDIM / 128, MDIM / 128), dim3(256), 0, stream>>>(
      x, W_enc, b_enc, mask_prev, hbuf);
  select_kernel<<<dim3(MDIM), dim3(256), 0, stream>>>(hbuf, mask_prev, hs);
  gemm2_kernel<<<dim3(ODIM / 128, MDIM / 128), dim3(256), 0, stream>>>(
      hs, wdec, b_dec, out);
}

// Round 2
// 855.878 us; speedup vs baseline: 1.0032x; 1.0032x over previous
//
#include <hip/hip_runtime.h>
#include <hip/hip_bf16.h>

typedef __attribute__((ext_vector_type(8))) __bf16 bf16x8;
typedef __attribute__((ext_vector_type(4))) float f32x4;

#define MDIM 16384  // B*T
#define HDIM 2048
#define IDIM 512
#define ODIM 512
#define CAP 768     // boundary-bin candidate buffer (typ. need ~10-60)

static __device__ __forceinline__ unsigned short f2bf(float f) {
  unsigned int u = __float_as_uint(f);
  unsigned int r = (u + 0x7fffu + ((u >> 16) & 1u)) >> 16;
  return (unsigned short)r;
}

// ---------------- W_dec f32 -> bf16 ----------------
__global__ void cvt_bf16_kernel(const float* __restrict__ src,
                                unsigned short* __restrict__ dst, int n) {
  int i = (blockIdx.x * 256 + threadIdx.x) * 4;
  if (i >= n) return;
  float4 v = *(const float4*)(src + i);
  unsigned int a = (unsigned int)f2bf(v.x) | ((unsigned int)f2bf(v.y) << 16);
  unsigned int b = (unsigned int)f2bf(v.z) | ((unsigned int)f2bf(v.w) << 16);
  uint2 st; st.x = a; st.y = b;
  *(uint2*)(dst + i) = st;
}

// ---------------- GEMM1: h = x @ W_enc^T + b_enc (raw; mask applied in select) ----
// f32 SIMT, 128x128 tile, BK=16, 256 threads, 8x8 micro-tile, register-prefetch
// pipeline: tile k+1 global loads issue right after the store barrier and drain
// while the 16-k FMA block runs.
__global__ __launch_bounds__(256) void gemm1_kernel(
    const float* __restrict__ x,     // [M, IDIM]
    const float* __restrict__ wenc,  // [HDIM, IDIM]
    const float* __restrict__ benc,  // [HDIM]
    float* __restrict__ h) {         // [M, HDIM]
  __shared__ __align__(16) float As[16][132];
  __shared__ __align__(16) float Bs[16][132];
  const int t = threadIdx.x;
  const int tx = t & 15, ty = t >> 4;
  const int m0 = blockIdx.y * 128;
  const int n0 = blockIdx.x * 128;
  const int r0 = t >> 2;
  const int k4 = (t & 3) * 4;

  const float* pa0 = x + (size_t)(m0 + r0) * IDIM + k4;
  const float* pa1 = x + (size_t)(m0 + 64 + r0) * IDIM + k4;
  const float* pb0 = wenc + (size_t)(n0 + r0) * IDIM + k4;
  const float* pb1 = wenc + (size_t)(n0 + 64 + r0) * IDIM + k4;

  float acc[8][8];
#pragma unroll
  for (int i = 0; i < 8; ++i)
#pragma unroll
    for (int j = 0; j < 8; ++j) acc[i][j] = 0.f;

  float4 a0 = *(const float4*)(pa0);
  float4 a1 = *(const float4*)(pa1);
  float4 b0 = *(const float4*)(pb0);
  float4 b1 = *(const float4*)(pb1);

  for (int kt = 0; kt < IDIM; kt += 16) {
    __syncthreads();
#pragma unroll
    for (int j = 0; j < 4; ++j) {
      As[k4 + j][r0]      = ((const float*)&a0)[j];
      As[k4 + j][64 + r0] = ((const float*)&a1)[j];
      Bs[k4 + j][r0]      = ((const float*)&b0)[j];
      Bs[k4 + j][64 + r0] = ((const float*)&b1)[j];
    }
    __syncthreads();
    if (kt + 16 < IDIM) {  // prefetch next tile; latency hides under FMA block
      a0 = *(const float4*)(pa0 + kt + 16);
      a1 = *(const float4*)(pa1 + kt + 16);
      b0 = *(const float4*)(pb0 + kt + 16);
      b1 = *(const float4*)(pb1 + kt + 16);
    }
#pragma unroll
    for (int k = 0; k < 16; ++k) {
      float4 av0 = *(const float4*)&As[k][ty * 4];
      float4 av1 = *(const float4*)&As[k][64 + ty * 4];
      float4 bv0 = *(const float4*)&Bs[k][tx * 4];
      float4 bv1 = *(const float4*)&Bs[k][64 + tx * 4];
      float am[8] = {av0.x, av0.y, av0.z, av0.w, av1.x, av1.y, av1.z, av1.w};
      float bm[8] = {bv0.x, bv0.y, bv0.z, bv0.w, bv1.x, bv1.y, bv1.z, bv1.w};
#pragma unroll
      for (int i = 0; i < 8; ++i)
#pragma unroll
        for (int j = 0; j < 8; ++j) acc[i][j] += am[i] * bm[j];
    }
  }
  float4 be0 = *(const float4*)(benc + n0 + tx * 4);
  float4 be1 = *(const float4*)(benc + n0 + 64 + tx * 4);
  float bb[8] = {be0.x, be0.y, be0.z, be0.w, be1.x, be1.y, be1.z, be1.w};
#pragma unroll
  for (int i = 0; i < 8; ++i) {
    int m = m0 + ((i < 4) ? (ty * 4 + i) : (64 + ty * 4 + (i - 4)));
    float* hrow = h + (size_t)m * HDIM + n0;
    float4 s0 = {acc[i][0] + bb[0], acc[i][1] + bb[1], acc[i][2] + bb[2], acc[i][3] + bb[3]};
    float4 s1 = {acc[i][4] + bb[4], acc[i][5] + bb[5], acc[i][6] + bb[6], acc[i][7] + bb[7]};
    *(float4*)(hrow + tx * 4) = s0;
    *(float4*)(hrow + 64 + tx * 4) = s1;
  }
}

// ---------------- selection v3: histogram radix-select ----------------
// One block (256 thr) per row. Applies the mask_prev exclusion itself.
// 4096-bin histogram of key>>20 (exact zeros skipped to avoid same-address
// atomic serialization), single-wave suffix scan locates boundary bin +
// residual rank for k=512 and k=256, boundary candidates gathered to LDS,
// 20-bit bisection on one wave each (waves 0/1 concurrently).
// Tie-fill in ascending index order == jax.lax.top_k semantics.
__global__ __launch_bounds__(256) void select_kernel(
    float* __restrict__ hbuf,           // in: raw h [M,HDIM]; out: mask_prev_new
    const int* __restrict__ maskp,      // [M, HDIM]
    unsigned short* __restrict__ hs) {  // out: h*mask_share as bf16 [M,HDIM]
  const int row = blockIdx.x;
  const int t = threadIdx.x;
  const int lane = t & 63;
  const int w = t >> 6;
  __shared__ int hist[4096];
  __shared__ unsigned int cand512[CAP];
  __shared__ unsigned int cand256[CAP];
  __shared__ int scal[16];
  __shared__ int n512, n256;

  float* hrow = hbuf + (size_t)row * HDIM;
  const int* mrow = maskp + (size_t)row * HDIM;
  float hv[8];
  *(float4*)&hv[0] = *(const float4*)(hrow + t * 8);
  *(float4*)&hv[4] = *(const float4*)(hrow + t * 8 + 4);
  int4 mp0 = *(const int4*)(mrow + t * 8);
  int4 mp1 = *(const int4*)(mrow + t * 8 + 4);
  int mm[8] = {mp0.x, mp0.y, mp0.z, mp0.w, mp1.x, mp1.y, mp1.z, mp1.w};
#pragma unroll
  for (int i = 0; i < 8; ++i) hv[i] = (mm[i] > 0) ? 0.f : hv[i];
  unsigned int key[8];
#pragma unroll
  for (int i = 0; i < 8; ++i) key[i] = __float_as_uint(hv[i] * hv[i]);

#pragma unroll
  for (int i = 0; i < 16; ++i) hist[t + i * 256] = 0;
  if (t == 0) {
    n512 = 0; n256 = 0;
    // defaults: bin 0, huge rank -> r > C -> v = 0 (fewer than k nonzero keys)
    scal[0] = 0; scal[1] = 0x40000000;
    scal[2] = 0; scal[3] = 0x40000000;
  }
  __syncthreads();
#pragma unroll
  for (int i = 0; i < 8; ++i)
    if (key[i]) atomicAdd(&hist[key[i] >> 20], 1);
  __syncthreads();

  if (w == 0) {  // suffix scan; lane owns bins [lane*64, lane*64+64)
    const int base = lane * 64;
    int s = 0;
#pragma unroll
    for (int i = 0; i < 64; i += 4) {
      int4 hh = *(const int4*)&hist[base + i];
      s += hh.x + hh.y + hh.z + hh.w;
    }
    int rs = s;  // inclusive suffix over lanes >= me
#pragma unroll
    for (int d = 1; d < 64; d <<= 1) {
      int o = __shfl_down(rs, d, 64);
      rs += (lane + d < 64) ? o : 0;
    }
    int c = rs - s;  // keys in bins strictly above my range
    for (int i = 60; i >= 0; i -= 4) {
      int4 hh = *(const int4*)&hist[base + i];
      int q[4] = {hh.x, hh.y, hh.z, hh.w};
#pragma unroll
      for (int j = 3; j >= 0; --j) {
        int hc = q[j];
        if (c < 512 && c + hc >= 512) { scal[0] = base + i + j; scal[1] = 512 - c; }
        if (c < 256 && c + hc >= 256) { scal[2] = base + i + j; scal[3] = 256 - c; }
        c += hc;
      }
    }
  }
  __syncthreads();
  const int b512 = scal[0], b256 = scal[2];
#pragma unroll
  for (int i = 0; i < 8; ++i) {
    if (key[i]) {
      int bin = (int)(key[i] >> 20);
      if (bin == b512) { int p = atomicAdd(&n512, 1); if (p < CAP) cand512[p] = key[i]; }
      if (bin == b256) { int p = atomicAdd(&n256, 1); if (p < CAP) cand256[p] = key[i]; }
    }
  }
  __syncthreads();

  if (w < 2) {  // wave 0: k=512 boundary; wave 1: k=256 boundary
    const unsigned int bb = (unsigned int)scal[w * 2];
    const int r = scal[w * 2 + 1];
    const unsigned int* cand = w ? cand256 : cand512;
    int C = w ? n256 : n512;
    C = (C < CAP) ? C : CAP;
    unsigned int v = 0;
    if (r <= C) {  // else: zeros pad the top-k -> boundary value is 0
      v = bb << 20;
      for (int bit = 19; bit >= 0; --bit) {
        unsigned int cth = v | (1u << bit);
        int cnt = 0;
        for (int p = lane; p < C; p += 64) cnt += (cand[p] >= cth) ? 1 : 0;
#pragma unroll
        for (int d = 1; d < 64; d <<= 1) cnt += __shfl_xor(cnt, d, 64);
        if (cnt >= r) v = cth;
      }
    }
    if (lane == 0) scal[4 + w] = (int)v;
  }
  __syncthreads();
  const unsigned int v512 = (unsigned int)scal[4];
  const unsigned int v256 = (unsigned int)scal[5];

  // ---- tie-break tail (identical structure to the verified round-1 kernel) ----
  int g = 0;
#pragma unroll
  for (int i = 0; i < 8; ++i) {
    g += (key[i] > v512) ? 1 : 0;
    g += (key[i] > v256) ? (1 << 16) : 0;
  }
#pragma unroll
  for (int d = 1; d < 64; d <<= 1) g += __shfl_xor(g, d, 64);
  if (lane == 0) scal[8 + w] = g;
  __syncthreads();
  g = scal[8] + scal[9] + scal[10] + scal[11];
  const int r512 = 512 - (g & 0xffff);
  const int r256 = 256 - (g >> 16);

  int tc = 0;
#pragma unroll
  for (int i = 0; i < 8; ++i) {
    tc += (key[i] == v512) ? 1 : 0;
    tc += (key[i] == v256) ? (1 << 16) : 0;
  }
  int sc = tc;
#pragma unroll
  for (int d = 1; d < 64; d <<= 1) {
    int o = __shfl_up(sc, d, 64);
    if (lane >= d) sc += o;
  }
  if (lane == 63) scal[12 + w] = sc;
  __syncthreads();
  int excl = sc - tc;
  for (int i = 0; i < w; ++i) excl += scal[12 + i];
  int run512 = excl & 0xffff;
  int run256 = (excl >> 16) & 0xffff;

  float mpn[8];
  unsigned int hb[4];
#pragma unroll
  for (int i = 0; i < 8; ++i) {
    bool share, cur;
    if (key[i] > v512) share = true;
    else if (key[i] == v512) { share = (run512 < r512); run512++; }
    else share = false;
    if (key[i] > v256) cur = true;
    else if (key[i] == v256) { cur = (run256 < r256); run256++; }
    else cur = false;
    mpn[i] = (float)mm[i] + (cur ? 1.0f : 0.0f);
    unsigned short bbits = f2bf(share ? hv[i] : 0.0f);
    if (i & 1) hb[i >> 1] |= ((unsigned int)bbits << 16);
    else hb[i >> 1] = (unsigned int)bbits;
  }
  float4 s0 = {mpn[0], mpn[1], mpn[2], mpn[3]};
  float4 s1 = {mpn[4], mpn[5], mpn[6], mpn[7]};
  *(float4*)(hrow + t * 8) = s0;
  *(float4*)(hrow + t * 8 + 4) = s1;
  uint4 hstore = {hb[0], hb[1], hb[2], hb[3]};
  *(uint4*)(hs + (size_t)row * HDIM + t * 8) = hstore;
}

// ---------------- GEMM2: out = hs @ W_dec^T + b_dec (bf16 MFMA, m97 pattern) ----
__global__ __launch_bounds__(256) void gemm2_kernel(
    const unsigned short* __restrict__ A,  // hs bf16 [M, HDIM]
    const unsigned short* __restrict__ B,  // W_dec bf16 [ODIM, HDIM]
    const float* __restrict__ bdec,        // [ODIM]
    float* __restrict__ out) {             // [M, ODIM] f32
  __shared__ __align__(16) __bf16 As[128 * 32];
  __shared__ __align__(16) __bf16 Bs[128 * 32];
  const int t = threadIdx.x;
  const int lane = t & 63;
  const int w = t >> 6;
  const int wm = w >> 1, wn = w & 1;
  const int m0 = blockIdx.y * 128;
  const int n0 = blockIdx.x * 128;
  const int r = t >> 2;
  const int k8 = (t & 3) * 8;

  f32x4 acc[4][4];
#pragma unroll
  for (int i = 0; i < 4; ++i)
#pragma unroll
    for (int j = 0; j < 4; ++j) acc[i][j] = (f32x4){0.f, 0.f, 0.f, 0.f};

  const int la = lane & 15;
  const int kq = (lane >> 4) * 8;

  for (int kt = 0; kt < HDIM; kt += 32) {
    uint4 a0 = *(const uint4*)(A + (size_t)(m0 + r) * HDIM + kt + k8);
    uint4 a1 = *(const uint4*)(A + (size_t)(m0 + 64 + r) * HDIM + kt + k8);
    uint4 b0 = *(const uint4*)(B + (size_t)(n0 + r) * HDIM + kt + k8);
    uint4 b1 = *(const uint4*)(B + (size_t)(n0 + 64 + r) * HDIM + kt + k8);
    __syncthreads();
    *(uint4*)&As[r * 32 + k8] = a0;
    *(uint4*)&As[(64 + r) * 32 + k8] = a1;
    *(uint4*)&Bs[r * 32 + k8] = b0;
    *(uint4*)&Bs[(64 + r) * 32 + k8] = b1;
    __syncthreads();
    bf16x8 af[4], bg[4];
#pragma unroll
    for (int mi = 0; mi < 4; ++mi)
      af[mi] = *(const bf16x8*)&As[(wm * 64 + mi * 16 + la) * 32 + kq];
#pragma unroll
    for (int ni = 0; ni < 4; ++ni)
      bg[ni] = *(const bf16x8*)&Bs[(wn * 64 + ni * 16 + la) * 32 + kq];
#pragma unroll
    for (int mi = 0; mi < 4; ++mi)
#pragma unroll
      for (int ni = 0; ni < 4; ++ni)
        acc[mi][ni] = __builtin_amdgcn_mfma_f32_16x16x32_bf16(
            af[mi], bg[ni], acc[mi][ni], 0, 0, 0);
  }
  const int rq = (lane >> 4) * 4;
#pragma unroll
  for (int mi = 0; mi < 4; ++mi) {
#pragma unroll
    for (int ni = 0; ni < 4; ++ni) {
      int n = n0 + wn * 64 + ni * 16 + la;
      float bd = bdec[n];
#pragma unroll
      for (int rr = 0; rr < 4; ++rr) {
        int m = m0 + wm * 64 + mi * 16 + rq + rr;
        out[(size_t)m * ODIM + n] = acc[mi][ni][rr] + bd;
      }
    }
  }
}

extern "C" void kernel_launch(void* const* d_in, const int* in_sizes, int n_in,
                              void* d_out, int out_size, void* d_ws, size_t ws_size,
                              hipStream_t stream) {
  const float* x = (const float*)d_in[0];
  const int* mask_prev = (const int*)d_in[1];
  const float* W_enc = (const float*)d_in[2];
  const float* b_enc = (const float*)d_in[3];
  const float* W_dec = (const float*)d_in[4];
  const float* b_dec = (const float*)d_in[5];

  float* out = (float*)d_out;
  float* hbuf = out + (size_t)MDIM * ODIM;          // h staged in mask_prev_new slot
  unsigned short* hs = (unsigned short*)d_ws;       // [M, HDIM] bf16
  unsigned short* wdec = hs + (size_t)MDIM * HDIM;  // [ODIM, HDIM] bf16

  cvt_bf16_kernel<<<dim3((ODIM * HDIM) / (256 * 4)), dim3(256), 0, stream>>>(
      W_dec, wdec, ODIM * HDIM);
  gemm1_kernel<<<dim3(HDIM / 128, MDIM / 128), dim3(256), 0, stream>>>(
      x, W_enc, b_enc, hbuf);
  select_kernel<<<dim3(MDIM), dim3(256), 0, stream>>>(hbuf, mask_prev, hs);
  gemm2_kernel<<<dim3(ODIM / 128, MDIM / 128), dim3(256), 0, stream>>>(
      hs, wdec, b_dec, out);
}

// Round 4
// 837.750 us; speedup vs baseline: 1.0249x; 1.0216x over previous
//
#include <hip/hip_runtime.h>
#include <hip/hip_bf16.h>

typedef __attribute__((ext_vector_type(8))) __bf16 bf16x8;
typedef __attribute__((ext_vector_type(4))) float f32x4;

#define MDIM 16384  // B*T
#define HDIM 2048
#define IDIM 512
#define ODIM 512
#define CAP 768     // boundary-bin candidate buffer

static __device__ __forceinline__ unsigned short f2bf(float f) {
  unsigned int u = __float_as_uint(f);
  unsigned int r = (u + 0x7fffu + ((u >> 16) & 1u)) >> 16;
  return (unsigned short)r;
}

// ---------------- W_dec f32 -> bf16 ----------------
__global__ void cvt_bf16_kernel(const float* __restrict__ src,
                                unsigned short* __restrict__ dst, int n) {
  int i = (blockIdx.x * 256 + threadIdx.x) * 4;
  if (i >= n) return;
  float4 v = *(const float4*)(src + i);
  unsigned int a = (unsigned int)f2bf(v.x) | ((unsigned int)f2bf(v.y) << 16);
  unsigned int b = (unsigned int)f2bf(v.z) | ((unsigned int)f2bf(v.w) << 16);
  uint2 st; st.x = a; st.y = b;
  *(uint2*)(dst + i) = st;
}

// ---------------- GEMM1: h = x @ W_enc^T + b_enc (f32; mask applied in select) ----
// 128x128 tile, BK=32 (32 barriers vs 64 at BK=16), 256 threads, 8x8 micro-tile.
// Global loads issue BEFORE the first barrier (overlap prior FMA block).
__global__ __launch_bounds__(256) void gemm1_kernel(
    const float* __restrict__ x,     // [M, IDIM]
    const float* __restrict__ wenc,  // [HDIM, IDIM]
    const float* __restrict__ benc,  // [HDIM]
    float* __restrict__ h) {         // [M, HDIM]
  __shared__ __align__(16) float As[32][132];  // [k][m], +4 pad
  __shared__ __align__(16) float Bs[32][132];  // [k][n]
  const int t = threadIdx.x;
  const int tx = t & 15, ty = t >> 4;
  const int m0 = blockIdx.y * 128;
  const int n0 = blockIdx.x * 128;
  const int r0 = t >> 1;          // 0..127 staging row
  const int kh = (t & 1) * 16;    // k sub-offset (0 or 16)

  const float* pa = x + (size_t)(m0 + r0) * IDIM + kh;
  const float* pb = wenc + (size_t)(n0 + r0) * IDIM + kh;

  float acc[8][8];
#pragma unroll
  for (int i = 0; i < 8; ++i)
#pragma unroll
    for (int j = 0; j < 8; ++j) acc[i][j] = 0.f;

  for (int kt = 0; kt < IDIM; kt += 32) {
    float4 a0 = *(const float4*)(pa + kt);
    float4 a1 = *(const float4*)(pa + kt + 4);
    float4 a2 = *(const float4*)(pa + kt + 8);
    float4 a3 = *(const float4*)(pa + kt + 12);
    float4 b0 = *(const float4*)(pb + kt);
    float4 b1 = *(const float4*)(pb + kt + 4);
    float4 b2 = *(const float4*)(pb + kt + 8);
    float4 b3 = *(const float4*)(pb + kt + 12);
    __syncthreads();
    {
      const float* aa = (const float*)&a0;  // a0..a3 contiguous? store explicitly
      const float av[16] = {a0.x, a0.y, a0.z, a0.w, a1.x, a1.y, a1.z, a1.w,
                            a2.x, a2.y, a2.z, a2.w, a3.x, a3.y, a3.z, a3.w};
      const float bv[16] = {b0.x, b0.y, b0.z, b0.w, b1.x, b1.y, b1.z, b1.w,
                            b2.x, b2.y, b2.z, b2.w, b3.x, b3.y, b3.z, b3.w};
      (void)aa;
#pragma unroll
      for (int j = 0; j < 16; ++j) {
        As[kh + j][r0] = av[j];
        Bs[kh + j][r0] = bv[j];
      }
    }
    __syncthreads();
#pragma unroll
    for (int k = 0; k < 32; ++k) {
      float4 av0 = *(const float4*)&As[k][ty * 4];
      float4 av1 = *(const float4*)&As[k][64 + ty * 4];
      float4 bv0 = *(const float4*)&Bs[k][tx * 4];
      float4 bv1 = *(const float4*)&Bs[k][64 + tx * 4];
      float am[8] = {av0.x, av0.y, av0.z, av0.w, av1.x, av1.y, av1.z, av1.w};
      float bm[8] = {bv0.x, bv0.y, bv0.z, bv0.w, bv1.x, bv1.y, bv1.z, bv1.w};
#pragma unroll
      for (int i = 0; i < 8; ++i)
#pragma unroll
        for (int j = 0; j < 8; ++j) acc[i][j] += am[i] * bm[j];
    }
  }
  float4 be0 = *(const float4*)(benc + n0 + tx * 4);
  float4 be1 = *(const float4*)(benc + n0 + 64 + tx * 4);
  float bb[8] = {be0.x, be0.y, be0.z, be0.w, be1.x, be1.y, be1.z, be1.w};
#pragma unroll
  for (int i = 0; i < 8; ++i) {
    int m = m0 + ((i < 4) ? (ty * 4 + i) : (64 + ty * 4 + (i - 4)));
    float* hrow = h + (size_t)m * HDIM + n0;
    float4 s0 = {acc[i][0] + bb[0], acc[i][1] + bb[1], acc[i][2] + bb[2], acc[i][3] + bb[3]};
    float4 s1 = {acc[i][4] + bb[4], acc[i][5] + bb[5], acc[i][6] + bb[6], acc[i][7] + bb[7]};
    *(float4*)(hrow + tx * 4) = s0;
    *(float4*)(hrow + 64 + tx * 4) = s1;
  }
}

// ---------------- selection v3: histogram radix-select (verified round 2) -----
__global__ __launch_bounds__(256) void select_kernel(
    float* __restrict__ hbuf,           // in: raw h [M,HDIM]; out: mask_prev_new
    const int* __restrict__ maskp,      // [M, HDIM]
    unsigned short* __restrict__ hs) {  // out: h*mask_share as bf16 [M,HDIM]
  const int row = blockIdx.x;
  const int t = threadIdx.x;
  const int lane = t & 63;
  const int w = t >> 6;
  __shared__ int hist[4096];
  __shared__ unsigned int cand512[CAP];
  __shared__ unsigned int cand256[CAP];
  __shared__ int scal[16];
  __shared__ int n512, n256;

  float* hrow = hbuf + (size_t)row * HDIM;
  const int* mrow = maskp + (size_t)row * HDIM;
  float hv[8];
  *(float4*)&hv[0] = *(const float4*)(hrow + t * 8);
  *(float4*)&hv[4] = *(const float4*)(hrow + t * 8 + 4);
  int4 mp0 = *(const int4*)(mrow + t * 8);
  int4 mp1 = *(const int4*)(mrow + t * 8 + 4);
  int mm[8] = {mp0.x, mp0.y, mp0.z, mp0.w, mp1.x, mp1.y, mp1.z, mp1.w};
#pragma unroll
  for (int i = 0; i < 8; ++i) hv[i] = (mm[i] > 0) ? 0.f : hv[i];
  unsigned int key[8];
#pragma unroll
  for (int i = 0; i < 8; ++i) key[i] = __float_as_uint(hv[i] * hv[i]);

#pragma unroll
  for (int i = 0; i < 16; ++i) hist[t + i * 256] = 0;
  if (t == 0) {
    n512 = 0; n256 = 0;
    scal[0] = 0; scal[1] = 0x40000000;
    scal[2] = 0; scal[3] = 0x40000000;
  }
  __syncthreads();
#pragma unroll
  for (int i = 0; i < 8; ++i)
    if (key[i]) atomicAdd(&hist[key[i] >> 20], 1);
  __syncthreads();

  if (w == 0) {
    const int base = lane * 64;
    int s = 0;
#pragma unroll
    for (int i = 0; i < 64; i += 4) {
      int4 hh = *(const int4*)&hist[base + i];
      s += hh.x + hh.y + hh.z + hh.w;
    }
    int rs = s;
#pragma unroll
    for (int d = 1; d < 64; d <<= 1) {
      int o = __shfl_down(rs, d, 64);
      rs += (lane + d < 64) ? o : 0;
    }
    int c = rs - s;
    for (int i = 60; i >= 0; i -= 4) {
      int4 hh = *(const int4*)&hist[base + i];
      int q[4] = {hh.x, hh.y, hh.z, hh.w};
#pragma unroll
      for (int j = 3; j >= 0; --j) {
        int hc = q[j];
        if (c < 512 && c + hc >= 512) { scal[0] = base + i + j; scal[1] = 512 - c; }
        if (c < 256 && c + hc >= 256) { scal[2] = base + i + j; scal[3] = 256 - c; }
        c += hc;
      }
    }
  }
  __syncthreads();
  const int b512 = scal[0], b256 = scal[2];
#pragma unroll
  for (int i = 0; i < 8; ++i) {
    if (key[i]) {
      int bin = (int)(key[i] >> 20);
      if (bin == b512) { int p = atomicAdd(&n512, 1); if (p < CAP) cand512[p] = key[i]; }
      if (bin == b256) { int p = atomicAdd(&n256, 1); if (p < CAP) cand256[p] = key[i]; }
    }
  }
  __syncthreads();

  if (w < 2) {
    const unsigned int bb = (unsigned int)scal[w * 2];
    const int r = scal[w * 2 + 1];
    const unsigned int* cand = w ? cand256 : cand512;
    int C = w ? n256 : n512;
    C = (C < CAP) ? C : CAP;
    unsigned int v = 0;
    if (r <= C) {
      v = bb << 20;
      for (int bit = 19; bit >= 0; --bit) {
        unsigned int cth = v | (1u << bit);
        int cnt = 0;
        for (int p = lane; p < C; p += 64) cnt += (cand[p] >= cth) ? 1 : 0;
#pragma unroll
        for (int d = 1; d < 64; d <<= 1) cnt += __shfl_xor(cnt, d, 64);
        if (cnt >= r) v = cth;
      }
    }
    if (lane == 0) scal[4 + w] = (int)v;
  }
  __syncthreads();
  const unsigned int v512 = (unsigned int)scal[4];
  const unsigned int v256 = (unsigned int)scal[5];

  int g = 0;
#pragma unroll
  for (int i = 0; i < 8; ++i) {
    g += (key[i] > v512) ? 1 : 0;
    g += (key[i] > v256) ? (1 << 16) : 0;
  }
#pragma unroll
  for (int d = 1; d < 64; d <<= 1) g += __shfl_xor(g, d, 64);
  if (lane == 0) scal[8 + w] = g;
  __syncthreads();
  g = scal[8] + scal[9] + scal[10] + scal[11];
  const int r512 = 512 - (g & 0xffff);
  const int r256 = 256 - (g >> 16);

  int tc = 0;
#pragma unroll
  for (int i = 0; i < 8; ++i) {
    tc += (key[i] == v512) ? 1 : 0;
    tc += (key[i] == v256) ? (1 << 16) : 0;
  }
  int sc = tc;
#pragma unroll
  for (int d = 1; d < 64; d <<= 1) {
    int o = __shfl_up(sc, d, 64);
    if (lane >= d) sc += o;
  }
  if (lane == 63) scal[12 + w] = sc;
  __syncthreads();
  int excl = sc - tc;
  for (int i = 0; i < w; ++i) excl += scal[12 + i];
  int run512 = excl & 0xffff;
  int run256 = (excl >> 16) & 0xffff;

  float mpn[8];
  unsigned int hb[4];
#pragma unroll
  for (int i = 0; i < 8; ++i) {
    bool share, cur;
    if (key[i] > v512) share = true;
    else if (key[i] == v512) { share = (run512 < r512); run512++; }
    else share = false;
    if (key[i] > v256) cur = true;
    else if (key[i] == v256) { cur = (run256 < r256); run256++; }
    else cur = false;
    mpn[i] = (float)mm[i] + (cur ? 1.0f : 0.0f);
    unsigned short bbits = f2bf(share ? hv[i] : 0.0f);
    if (i & 1) hb[i >> 1] |= ((unsigned int)bbits << 16);
    else hb[i >> 1] = (unsigned int)bbits;
  }
  float4 s0 = {mpn[0], mpn[1], mpn[2], mpn[3]};
  float4 s1 = {mpn[4], mpn[5], mpn[6], mpn[7]};
  *(float4*)(hrow + t * 8) = s0;
  *(float4*)(hrow + t * 8 + 4) = s1;
  uint4 hstore = {hb[0], hb[1], hb[2], hb[3]};
  *(uint4*)(hs + (size_t)row * HDIM + t * 8) = hstore;
}

// ---------------- GEMM2: out = hs @ W_dec^T + b_dec (bf16 MFMA) ----------------
// 64x128 (MxN) tile, BK=32, 256 thr / 4 waves in 2x2; wave = 32x64 (2x4 subtiles).
// Grid 1024 blocks (4 blocks/CU) for latency hiding at K=2048.
__global__ __launch_bounds__(256) void gemm2_kernel(
    const unsigned short* __restrict__ A,  // hs bf16 [M, HDIM]
    const unsigned short* __restrict__ B,  // W_dec bf16 [ODIM, HDIM]
    const float* __restrict__ bdec,        // [ODIM]
    float* __restrict__ out) {             // [M, ODIM] f32
  __shared__ __align__(16) __bf16 As[64 * 32];
  __shared__ __align__(16) __bf16 Bs[128 * 32];
  const int t = threadIdx.x;
  const int lane = t & 63;
  const int w = t >> 6;
  const int wm = w >> 1, wn = w & 1;
  const int m0 = blockIdx.y * 64;
  const int n0 = blockIdx.x * 128;
  const int r = t >> 2;          // staging row 0..63
  const int k8 = (t & 3) * 8;

  f32x4 acc[2][4];
#pragma unroll
  for (int i = 0; i < 2; ++i)
#pragma unroll
    for (int j = 0; j < 4; ++j) acc[i][j] = (f32x4){0.f, 0.f, 0.f, 0.f};

  const int la = lane & 15;
  const int kq = (lane >> 4) * 8;

  for (int kt = 0; kt < HDIM; kt += 32) {
    uint4 a0 = *(const uint4*)(A + (size_t)(m0 + r) * HDIM + kt + k8);
    uint4 b0 = *(const uint4*)(B + (size_t)(n0 + r) * HDIM + kt + k8);
    uint4 b1 = *(const uint4*)(B + (size_t)(n0 + 64 + r) * HDIM + kt + k8);
    __syncthreads();
    *(uint4*)&As[r * 32 + k8] = a0;
    *(uint4*)&Bs[r * 32 + k8] = b0;
    *(uint4*)&Bs[(64 + r) * 32 + k8] = b1;
    __syncthreads();
    bf16x8 af[2], bg[4];
#pragma unroll
    for (int mi = 0; mi < 2; ++mi)
      af[mi] = *(const bf16x8*)&As[(wm * 32 + mi * 16 + la) * 32 + kq];
#pragma unroll
    for (int ni = 0; ni < 4; ++ni)
      bg[ni] = *(const bf16x8*)&Bs[(wn * 64 + ni * 16 + la) * 32 + kq];
#pragma unroll
    for (int mi = 0; mi < 2; ++mi)
#pragma unroll
      for (int ni = 0; ni < 4; ++ni)
        acc[mi][ni] = __builtin_amdgcn_mfma_f32_16x16x32_bf16(
            af[mi], bg[ni], acc[mi][ni], 0, 0, 0);
  }
  // C/D: col = lane&15, row = (lane>>4)*4 + reg
  const int rq = (lane >> 4) * 4;
#pragma unroll
  for (int mi = 0; mi < 2; ++mi) {
#pragma unroll
    for (int ni = 0; ni < 4; ++ni) {
      int n = n0 + wn * 64 + ni * 16 + la;
      float bd = bdec[n];
#pragma unroll
      for (int rr = 0; rr < 4; ++rr) {
        int m = m0 + wm * 32 + mi * 16 + rq + rr;
        out[(size_t)m * ODIM + n] = acc[mi][ni][rr] + bd;
      }
    }
  }
}

extern "C" void kernel_launch(void* const* d_in, const int* in_sizes, int n_in,
                              void* d_out, int out_size, void* d_ws, size_t ws_size,
                              hipStream_t stream) {
  const float* x = (const float*)d_in[0];
  const int* mask_prev = (const int*)d_in[1];
  const float* W_enc = (const float*)d_in[2];
  const float* b_enc = (const float*)d_in[3];
  const float* W_dec = (const float*)d_in[4];
  const float* b_dec = (const float*)d_in[5];

  float* out = (float*)d_out;
  float* hbuf = out + (size_t)MDIM * ODIM;          // h / mask_prev_new slot
  unsigned short* hs = (unsigned short*)d_ws;       // [M, HDIM] bf16
  unsigned short* wdec = hs + (size_t)MDIM * HDIM;  // [ODIM, HDIM] bf16

  cvt_bf16_kernel<<<dim3((ODIM * HDIM) / (256 * 4)), dim3(256), 0, stream>>>(
      W_dec, wdec, ODIM * HDIM);
  gemm1_kernel<<<dim3(HDIM / 128, MDIM / 128), dim3(256), 0, stream>>>(
      x, W_enc, b_enc, hbuf);
  select_kernel<<<dim3(MDIM), dim3(256), 0, stream>>>(hbuf, mask_prev, hs);
  gemm2_kernel<<<dim3(ODIM / 128, MDIM / 64), dim3(256), 0, stream>>>(
      hs, wdec, b_dec, out);
}